// Round 4
// baseline (274.190 us; speedup 1.0000x reference)
//
#include <hip/hip_runtime.h>

#define N_NODES 75000
#define N_EDGES 1200000
#define DIM 64
#define SCAN_BLK 1024
#define N_SCAN_BLKS ((N_NODES + SCAN_BLK - 1) / SCAN_BLK)   // 74
#define NCOPY 8
#define HIST_BLKS ((N_EDGES + 1023) / 1024)                 // 1172, 1024 edges/block
#define NW_BLKS 1024                                        // node_wave part of fat kernel
#define FAT_BLKS (HIST_BLKS + NW_BLKS)

// Broadcast lane l (wave-uniform) of v to all lanes via v_readlane (VALU).
__device__ __forceinline__ float lane_bcf(float v, int l) {
    return __int_as_float(__builtin_amdgcn_readlane(__float_as_int(v), l));
}
__device__ __forceinline__ int lane_bci(int v, int l) {
    return __builtin_amdgcn_readlane(v, l);
}

// ---------------------------------------------------------------------------
// FAT KERNEL: hist (blocks 0..HIST_BLKS-1) + node_wave (rest).
// R3 post-mortem: fusion gave ZERO overlap because node_wave's streaming
// traffic (p_u/d_u reads, wv stores, + per-wave w_k/w_q recompute = 134 MB
// of redundant L2 reads) evicted cnt8 from L2, collapsing the atomic rate.
// R4 fix: (a) ALL single-touch streams use nontemporal loads/stores so they
// don't displace cnt8 (the only buffer that needs L2 residency);
// (b) a/b are computed ONCE PER BLOCK into LDS (4x less w_k/w_q traffic).
// hist blocks FIRST so blockIdx&7 = XCD id (cnt8 copy stays XCD-local).
// ---------------------------------------------------------------------------
__global__ __launch_bounds__(256, 4) void fat_kernel(
    const int* __restrict__ dst, int* __restrict__ cnt8, int* __restrict__ rank,
    const float* __restrict__ d_u, const float* __restrict__ p_u,
    const float* __restrict__ w_v, const float* __restrict__ w_q,
    const float* __restrict__ w_k,
    const float* __restrict__ e1, const float* __restrict__ e2,
    double* __restrict__ h_src, double* __restrict__ h_dst,
    float* __restrict__ wv_out) {

    if (blockIdx.x < HIST_BLKS) {
        // ---- histogram path ----
        int base = blockIdx.x << 10;                 // 1024 edges per block
        int* mycnt = cnt8 + (size_t)(blockIdx.x & (NCOPY - 1)) * N_NODES;
        #pragma unroll
        for (int k = 0; k < 4; ++k) {
            int e = base + k * 256 + threadIdx.x;
            if (e < N_EDGES) {
                int d = __builtin_nontemporal_load(&dst[e]);
                int r = atomicAdd(&mycnt[d], 1);
                __builtin_nontemporal_store(r, &rank[e]);
            }
        }
        return;
    }

    // ---- node_wave path: ONE WAVE PER NODE (grid-strided) ----
    __shared__ double al_sh[DIM];
    __shared__ double bl_sh[DIM];
    int lane = threadIdx.x & 63;

    // a[d] = sum_j e1[j]*w_k[j][d]; b[d] = sum_j e2[j]*w_q[j][d] — computed
    // once per BLOCK (wave 0), f64, same j-order as original (bit-exact).
    if (threadIdx.x < DIM) {
        double al = 0.0, bl = 0.0;
        #pragma unroll 8
        for (int j = 0; j < DIM; ++j) {
            al += (double)e1[j] * (double)w_k[j * DIM + threadIdx.x];
            bl += (double)e2[j] * (double)w_q[j * DIM + threadIdx.x];
        }
        al_sh[threadIdx.x] = al;
        bl_sh[threadIdx.x] = bl;
    }

    float w[DIM];
    const float4* wr = (const float4*)(w_v + (size_t)lane * DIM);
    #pragma unroll
    for (int k = 0; k < DIM / 4; ++k) {
        float4 v = wr[k];
        w[4 * k + 0] = v.x; w[4 * k + 1] = v.y;
        w[4 * k + 2] = v.z; w[4 * k + 3] = v.w;
    }
    __syncthreads();
    double al = al_sh[lane];
    double bl = bl_sh[lane];

    int wave = ((blockIdx.x - HIST_BLKS) * 256 + threadIdx.x) >> 6;
    int nwaves = NW_BLKS * 4;

    for (int i = wave; i < N_NODES; i += nwaves) {
        float pl = __builtin_nontemporal_load(&p_u[(size_t)i * DIM + lane]);
        float dl = __builtin_nontemporal_load(&d_u[(size_t)i * DIM + lane]);

        double hs = (double)pl * al;
        #pragma unroll
        for (int off = 32; off > 0; off >>= 1) hs += __shfl_xor(hs, off, 64);
        double hd = (double)dl * bl;
        #pragma unroll
        for (int off = 32; off > 0; off >>= 1) hd += __shfl_xor(hd, off, 64);
        if (lane == 0) {
            __builtin_nontemporal_store(hs, &h_src[i]);
            __builtin_nontemporal_store(hd, &h_dst[i]);
        }

        float a0 = 0.f, a1 = 0.f, a2 = 0.f, a3 = 0.f;
        #pragma unroll
        for (int d = 0; d < DIM; d += 4) {
            a0 += w[d + 0] * lane_bcf(pl, d + 0);
            a1 += w[d + 1] * lane_bcf(pl, d + 1);
            a2 += w[d + 2] * lane_bcf(pl, d + 2);
            a3 += w[d + 3] * lane_bcf(pl, d + 3);
        }
        __builtin_nontemporal_store((a0 + a1) + (a2 + a3),
                                    &wv_out[(size_t)i * DIM + lane]);
    }
}

// CSR step 2a: fold the 8 copies (in-place exclusive prefix over copies ->
// per-copy base offsets for build), total degree -> cnt; then per-block
// exclusive scan of totals (Hillis-Steele in LDS).
__global__ __launch_bounds__(SCAN_BLK) void scan1_kernel(
    int* __restrict__ cnt8, int* __restrict__ cnt,
    int* __restrict__ row, int* __restrict__ bsum) {
    __shared__ int sh[SCAN_BLK];
    int tid = threadIdx.x;
    int i = blockIdx.x * SCAN_BLK + tid;
    int v = 0;
    if (i < N_NODES) {
        int run = 0;
        #pragma unroll
        for (int c = 0; c < NCOPY; ++c) {
            int x = cnt8[(size_t)c * N_NODES + i];
            cnt8[(size_t)c * N_NODES + i] = run;   // P[c][i] = prefix
            run += x;
        }
        v = run;
        cnt[i] = run;                              // degree
    }
    sh[tid] = v;
    __syncthreads();
    for (int off = 1; off < SCAN_BLK; off <<= 1) {
        int t = (tid >= off) ? sh[tid - off] : 0;
        __syncthreads();
        sh[tid] += t;
        __syncthreads();
    }
    if (i < N_NODES) row[i] = sh[tid] - v;   // exclusive
    if (tid == SCAN_BLK - 1) bsum[blockIdx.x] = sh[tid];
}

// CSR step 2b: add block-sum prefix (redundant tiny scan per block).
__global__ __launch_bounds__(256) void scan23_kernel(
    int* __restrict__ row, const int* __restrict__ bsum) {
    __shared__ int pref[N_SCAN_BLKS];
    int tid = threadIdx.x;
    if (tid == 0) {
        int run = 0;
        #pragma unroll 8
        for (int k = 0; k < N_SCAN_BLKS; ++k) { pref[k] = run; run += bsum[k]; }
    }
    __syncthreads();
    int i = blockIdx.x * 256 + tid;
    if (i >= N_NODES) return;
    row[i] += pref[i / SCAN_BLK];
}

// CSR step 3: atomic-free scatter of src ids.
//   pos = row[d] + P[copy(e)][d] + rank[e],  copy(e) = (e>>10)&7.
__global__ __launch_bounds__(256) void build_kernel(
    const int* __restrict__ src, const int* __restrict__ dst,
    const int* __restrict__ row, const int* __restrict__ cnt8,
    const int* __restrict__ rank, int* __restrict__ csr_src) {
    int e = blockIdx.x * 256 + threadIdx.x;
    if (e >= N_EDGES) return;
    int d = dst[e];
    int copy = (e >> 10) & (NCOPY - 1);
    int pos = row[d] + cnt8[(size_t)copy * N_NODES + d] + rank[e];
    csr_src[pos] = src[e];
}

// ---------------------------------------------------------------------------
// Gather: one wave per dst node, grouped float4 row gather — 4 groups of 16
// lanes each load a DIFFERENT edge's 256B wv row as float4 (one dwordx4
// covers 4 rows). f64 butterfly denom kept; rounds skipped for small deg.
// ---------------------------------------------------------------------------
__global__ __launch_bounds__(256) void node_gather(
    const int* __restrict__ row, const int* __restrict__ cnt,
    const int* __restrict__ csr_src,
    const double* __restrict__ h_src, const double* __restrict__ h_dst,
    const float* __restrict__ wv, float* __restrict__ out) {
    int gtid = blockIdx.x * 256 + threadIdx.x;
    int node = gtid >> 6;
    int lane = threadIdx.x & 63;
    if (node >= N_NODES) return;

    int start = row[node];
    int deg = cnt[node];
    double hd = h_dst[node];

    if (deg <= 64) {
        int s0 = 0;
        double c0 = 0.0;
        if (lane < deg) {
            s0 = csr_src[start + lane];
            c0 = h_src[s0] + hd;
        }
        double r = c0;
        if (deg > 32) r += __shfl_xor(r, 32, 64);
        if (deg > 16) r += __shfl_xor(r, 16, 64);
        r += __shfl_xor(r, 8, 64);
        r += __shfl_xor(r, 4, 64);
        r += __shfl_xor(r, 2, 64);
        r += __shfl_xor(r, 1, 64);
        double inv = 1.0 / r;
        float cf0 = (lane < deg) ? (float)(c0 * inv) : 0.f;
        // padded lanes (>= deg): s0 = 0 (valid row), cf0 = 0 -> no-op terms.

        int g = lane >> 4;          // group 0..3 = which edge of the quartet
        int sub = lane & 15;        // float4 slot within the 256B row
        float ax = 0.f, ay = 0.f, az = 0.f, aw = 0.f;
        int rounds = (deg + 3) >> 2;
        int j = 0;
        for (; j + 2 <= rounds; j += 2) {
            int l0 = 4 * j + g;
            int l1 = l0 + 4;
            int   sA = __shfl(s0, l0, 64);
            float cA = __shfl(cf0, l0, 64);
            int   sB = __shfl(s0, l1, 64);
            float cB = __shfl(cf0, l1, 64);
            float4 vA = ((const float4*)(wv + (size_t)sA * DIM))[sub];
            float4 vB = ((const float4*)(wv + (size_t)sB * DIM))[sub];
            ax += vA.x * cA; ay += vA.y * cA; az += vA.z * cA; aw += vA.w * cA;
            ax += vB.x * cB; ay += vB.y * cB; az += vB.z * cB; aw += vB.w * cB;
        }
        if (j < rounds) {
            int l0 = 4 * j + g;
            int   sA = __shfl(s0, l0, 64);
            float cA = __shfl(cf0, l0, 64);
            float4 vA = ((const float4*)(wv + (size_t)sA * DIM))[sub];
            ax += vA.x * cA; ay += vA.y * cA; az += vA.z * cA; aw += vA.w * cA;
        }
        ax += __shfl_xor(ax, 16, 64); ay += __shfl_xor(ay, 16, 64);
        az += __shfl_xor(az, 16, 64); aw += __shfl_xor(aw, 16, 64);
        ax += __shfl_xor(ax, 32, 64); ay += __shfl_xor(ay, 32, 64);
        az += __shfl_xor(az, 32, 64); aw += __shfl_xor(aw, 32, 64);
        if (g == 0) {
            float4 o; o.x = ax; o.y = ay; o.z = az; o.w = aw;
            ((float4*)(out + (size_t)node * DIM))[sub] = o;
        }
    } else {
        double denom = 0.0;
        for (int base = 0; base < deg; base += 64) {
            int m = deg - base; if (m > 64) m = 64;
            double c = 0.0;
            if (lane < m) {
                int s = csr_src[start + base + lane];
                c = h_src[s] + hd;
            }
            #pragma unroll
            for (int off = 32; off > 0; off >>= 1) c += __shfl_xor(c, off, 64);
            denom += c;
        }
        double inv = 1.0 / denom;
        float acc = 0.f;
        for (int base = 0; base < deg; base += 64) {
            int m = deg - base; if (m > 64) m = 64;
            int s1 = 0; float cf1 = 0.f;
            if (lane < m) {
                s1 = csr_src[start + base + lane];
                cf1 = (float)((h_src[s1] + hd) * inv);
            }
            for (int j = 0; j < m; ++j) {
                int s = lane_bci(s1, j);
                float cf = lane_bcf(cf1, j);
                acc += wv[(size_t)s * DIM + lane] * cf;
            }
        }
        out[(size_t)node * DIM + lane] = acc;
    }
}

// ---------------------------------------------------------------------------
// Launch
// ---------------------------------------------------------------------------
extern "C" void kernel_launch(void* const* d_in, const int* in_sizes, int n_in,
                              void* d_out, int out_size, void* d_ws, size_t ws_size,
                              hipStream_t stream) {
    const float* d_u = (const float*)d_in[0];
    const float* p_u = (const float*)d_in[1];
    const float* w_q = (const float*)d_in[2];
    const float* w_k = (const float*)d_in[3];
    const float* w_v = (const float*)d_in[4];
    const float* e1  = (const float*)d_in[5];
    const float* e2  = (const float*)d_in[6];
    const int*   src = (const int*)d_in[7];
    const int*   dst = (const int*)d_in[8];
    float* out = (float*)d_out;

    // Workspace: doubles first (8B aligned), then floats, then ints.
    double* h_src  = (double*)d_ws;
    double* h_dst  = h_src + N_NODES;
    float*  wv     = (float*)(h_dst + N_NODES);       // N_NODES*DIM floats
    int*    cnt    = (int*)(wv + (size_t)N_NODES * DIM);
    int*    row    = cnt + N_NODES;
    int*    bsum   = row + N_NODES;                   // 128 ints
    int*    cnt8   = bsum + 128;                      // NCOPY*N_NODES ints
    int*    rank   = cnt8 + (size_t)NCOPY * N_NODES;  // N_EDGES ints
    int*    csr_src= rank + N_EDGES;                  // N_EDGES ints

    hipMemsetAsync(cnt8, 0, sizeof(int) * (size_t)NCOPY * N_NODES, stream);

    fat_kernel<<<FAT_BLKS, 256, 0, stream>>>(
        dst, cnt8, rank, d_u, p_u, w_v, w_q, w_k, e1, e2, h_src, h_dst, wv);

    scan1_kernel<<<N_SCAN_BLKS, SCAN_BLK, 0, stream>>>(cnt8, cnt, row, bsum);
    scan23_kernel<<<(N_NODES + 255) / 256, 256, 0, stream>>>(row, bsum);

    build_kernel<<<(N_EDGES + 255) / 256, 256, 0, stream>>>(
        src, dst, row, cnt8, rank, csr_src);

    node_gather<<<(N_NODES * 64 + 255) / 256, 256, 0, stream>>>(
        row, cnt, csr_src, h_src, h_dst, wv, out);
}

// Round 5
// 263.293 us; speedup vs baseline: 1.0414x; 1.0414x over previous
//
#include <hip/hip_runtime.h>

#define N_NODES 75000
#define N_EDGES 1200000
#define DIM 64
#define SCAN_BLK 1024
#define N_SCAN_BLKS ((N_NODES + SCAN_BLK - 1) / SCAN_BLK)   // 74
#define NCOPY 8
#define HIST_EPB 2048                                       // edges per hist block
#define HIST_BLKS ((N_EDGES + HIST_EPB - 1) / HIST_EPB)     // 586

// Broadcast lane l (wave-uniform) of v to all lanes via v_readlane (VALU).
__device__ __forceinline__ float lane_bcf(float v, int l) {
    return __int_as_float(__builtin_amdgcn_readlane(__float_as_int(v), l));
}
__device__ __forceinline__ int lane_bci(int v, int l) {
    return __builtin_amdgcn_readlane(v, l);
}

// ---------------------------------------------------------------------------
// Kernel A (f64): a[d] = sum_j e1[j]*w_k[j][d];  b[d] = sum_j e2[j]*w_q[j][d]
// ---------------------------------------------------------------------------
__global__ void vec_precompute(const float* __restrict__ w_q,
                               const float* __restrict__ w_k,
                               const float* __restrict__ e1,
                               const float* __restrict__ e2,
                               double* __restrict__ a,
                               double* __restrict__ b) {
    int t = threadIdx.x;
    if (t < DIM) {
        double s = 0.0;
        #pragma unroll
        for (int j = 0; j < DIM; ++j) s += (double)e1[j] * (double)w_k[j * DIM + t];
        a[t] = s;
    } else if (t < 2 * DIM) {
        int d = t - DIM;
        double s = 0.0;
        #pragma unroll
        for (int j = 0; j < DIM; ++j) s += (double)e2[j] * (double)w_q[j * DIM + d];
        b[d] = s;
    }
}

// ---------------------------------------------------------------------------
// Fused node precompute: ONE WAVE PER NODE (grid-strided). R2 version
// restored (no nt hints — R4 showed nt-producing consumer-read buffers
// converts downstream L2/L3 hits into HBM misses: total 254 -> 274).
// ---------------------------------------------------------------------------
__global__ __launch_bounds__(256, 4) void node_wave(
    const float* __restrict__ d_u, const float* __restrict__ p_u,
    const float* __restrict__ w_v,
    const double* __restrict__ a_vec, const double* __restrict__ b_vec,
    double* __restrict__ h_src, double* __restrict__ h_dst,
    float* __restrict__ wv_out) {
    int lane = threadIdx.x & 63;
    int wave = (blockIdx.x * 256 + threadIdx.x) >> 6;
    int nwaves = gridDim.x * 4;

    float w[DIM];
    const float4* wr = (const float4*)(w_v + (size_t)lane * DIM);
    #pragma unroll
    for (int k = 0; k < DIM / 4; ++k) {
        float4 v = wr[k];
        w[4 * k + 0] = v.x; w[4 * k + 1] = v.y;
        w[4 * k + 2] = v.z; w[4 * k + 3] = v.w;
    }
    double al = a_vec[lane];
    double bl = b_vec[lane];

    for (int i = wave; i < N_NODES; i += nwaves) {
        float pl = p_u[(size_t)i * DIM + lane];
        float dl = d_u[(size_t)i * DIM + lane];

        double hs = (double)pl * al;
        #pragma unroll
        for (int off = 32; off > 0; off >>= 1) hs += __shfl_xor(hs, off, 64);
        double hd = (double)dl * bl;
        #pragma unroll
        for (int off = 32; off > 0; off >>= 1) hd += __shfl_xor(hd, off, 64);
        if (lane == 0) { h_src[i] = hs; h_dst[i] = hd; }

        float a0 = 0.f, a1 = 0.f, a2 = 0.f, a3 = 0.f;
        #pragma unroll
        for (int d = 0; d < DIM; d += 4) {
            a0 += w[d + 0] * lane_bcf(pl, d + 0);
            a1 += w[d + 1] * lane_bcf(pl, d + 1);
            a2 += w[d + 2] * lane_bcf(pl, d + 2);
            a3 += w[d + 3] * lane_bcf(pl, d + 3);
        }
        wv_out[(size_t)i * DIM + lane] = (a0 + a1) + (a2 + a3);
    }
}

// ---------------------------------------------------------------------------
// CSR step 1: XCD-privatized histogram — NOW KEYED BY THE REAL XCD ID.
// R2's WRITE_SIZE=42MB (vs ~7MB true output) showed cnt8 lines written back
// ~17x: the blockIdx&7 -> XCD heuristic does NOT hold, so "private" copies
// ping-ponged between XCD L2s. s_getreg(HW_REG_XCC_ID) [HW-verified on
// MI355X] guarantees each copy is touched by exactly one XCD's L2.
// Since build can't recompute the copy, pack it into rank's high bits
// (rank < 2^28 always; NCOPY=8 -> 3 bits at bit 28).
// 8 edges/thread for atomic memory-level parallelism.
// ---------------------------------------------------------------------------
__global__ __launch_bounds__(256) void hist_kernel(
    const int* __restrict__ dst, int* __restrict__ cnt8,
    int* __restrict__ rank) {
    int xcc;
    asm("s_getreg_b32 %0, hwreg(HW_REG_XCC_ID)" : "=s"(xcc));
    xcc &= (NCOPY - 1);
    int* mycnt = cnt8 + (size_t)xcc * N_NODES;
    int tag = xcc << 28;
    int base = blockIdx.x * HIST_EPB;
    #pragma unroll
    for (int k = 0; k < HIST_EPB / 256; ++k) {
        int e = base + k * 256 + threadIdx.x;
        if (e < N_EDGES) {
            int r = atomicAdd(&mycnt[dst[e]], 1);
            rank[e] = r | tag;
        }
    }
}

// CSR step 2a: fold the 8 copies (in-place exclusive prefix over copies ->
// per-copy base offsets for build), total degree -> cnt; then per-block
// exclusive scan of totals (Hillis-Steele in LDS).
__global__ __launch_bounds__(SCAN_BLK) void scan1_kernel(
    int* __restrict__ cnt8, int* __restrict__ cnt,
    int* __restrict__ row, int* __restrict__ bsum) {
    __shared__ int sh[SCAN_BLK];
    int tid = threadIdx.x;
    int i = blockIdx.x * SCAN_BLK + tid;
    int v = 0;
    if (i < N_NODES) {
        int run = 0;
        #pragma unroll
        for (int c = 0; c < NCOPY; ++c) {
            int x = cnt8[(size_t)c * N_NODES + i];
            cnt8[(size_t)c * N_NODES + i] = run;   // P[c][i] = prefix
            run += x;
        }
        v = run;
        cnt[i] = run;                              // degree
    }
    sh[tid] = v;
    __syncthreads();
    for (int off = 1; off < SCAN_BLK; off <<= 1) {
        int t = (tid >= off) ? sh[tid - off] : 0;
        __syncthreads();
        sh[tid] += t;
        __syncthreads();
    }
    if (i < N_NODES) row[i] = sh[tid] - v;   // exclusive
    if (tid == SCAN_BLK - 1) bsum[blockIdx.x] = sh[tid];
}

// CSR step 2b: add block-sum prefix. Parallelized: 128-thread Hillis-Steele
// over the 74 block sums (was a serial 74-iter loop in thread 0).
__global__ __launch_bounds__(256) void scan23_kernel(
    int* __restrict__ row, const int* __restrict__ bsum) {
    __shared__ int pref[128];
    int tid = threadIdx.x;
    int v = 0;
    if (tid < 128) {
        v = (tid < N_SCAN_BLKS) ? bsum[tid] : 0;
        pref[tid] = v;
    }
    __syncthreads();
    #pragma unroll
    for (int off = 1; off < 128; off <<= 1) {
        int t = 0;
        if (tid < 128 && tid >= off) t = pref[tid - off];
        __syncthreads();
        if (tid < 128) pref[tid] += t;
        __syncthreads();
    }
    if (tid < 128) pref[tid] -= v;           // inclusive -> exclusive
    __syncthreads();
    int i = blockIdx.x * 256 + tid;
    if (i >= N_NODES) return;
    row[i] += pref[i / SCAN_BLK];
}

// CSR step 3: atomic-free scatter of src ids.
//   pos = row[d] + P[copy][d] + r,  where rank[e] packs (copy<<28 | r).
__global__ __launch_bounds__(256) void build_kernel(
    const int* __restrict__ src, const int* __restrict__ dst,
    const int* __restrict__ row, const int* __restrict__ cnt8,
    const int* __restrict__ rank, int* __restrict__ csr_src) {
    int e = blockIdx.x * 256 + threadIdx.x;
    if (e >= N_EDGES) return;
    int d = dst[e];
    int rp = rank[e];
    int copy = (rp >> 28) & (NCOPY - 1);
    int r = rp & 0x0FFFFFFF;
    int pos = row[d] + cnt8[(size_t)copy * N_NODES + d] + r;
    csr_src[pos] = src[e];
}

// ---------------------------------------------------------------------------
// Gather: one wave per dst node, grouped float4 row gather — 4 groups of 16
// lanes each load a DIFFERENT edge's 256B wv row as float4 (one dwordx4
// covers 4 rows). f64 butterfly denom kept; rounds skipped for small deg.
// ---------------------------------------------------------------------------
__global__ __launch_bounds__(256) void node_gather(
    const int* __restrict__ row, const int* __restrict__ cnt,
    const int* __restrict__ csr_src,
    const double* __restrict__ h_src, const double* __restrict__ h_dst,
    const float* __restrict__ wv, float* __restrict__ out) {
    int gtid = blockIdx.x * 256 + threadIdx.x;
    int node = gtid >> 6;
    int lane = threadIdx.x & 63;
    if (node >= N_NODES) return;

    int start = row[node];
    int deg = cnt[node];
    double hd = h_dst[node];

    if (deg <= 64) {
        int s0 = 0;
        double c0 = 0.0;
        if (lane < deg) {
            s0 = csr_src[start + lane];
            c0 = h_src[s0] + hd;
        }
        double r = c0;
        if (deg > 32) r += __shfl_xor(r, 32, 64);
        if (deg > 16) r += __shfl_xor(r, 16, 64);
        r += __shfl_xor(r, 8, 64);
        r += __shfl_xor(r, 4, 64);
        r += __shfl_xor(r, 2, 64);
        r += __shfl_xor(r, 1, 64);
        double inv = 1.0 / r;
        float cf0 = (lane < deg) ? (float)(c0 * inv) : 0.f;
        // padded lanes (>= deg): s0 = 0 (valid row), cf0 = 0 -> no-op terms.

        int g = lane >> 4;          // group 0..3 = which edge of the quartet
        int sub = lane & 15;        // float4 slot within the 256B row
        float ax = 0.f, ay = 0.f, az = 0.f, aw = 0.f;
        int rounds = (deg + 3) >> 2;
        int j = 0;
        for (; j + 2 <= rounds; j += 2) {
            int l0 = 4 * j + g;
            int l1 = l0 + 4;
            int   sA = __shfl(s0, l0, 64);
            float cA = __shfl(cf0, l0, 64);
            int   sB = __shfl(s0, l1, 64);
            float cB = __shfl(cf0, l1, 64);
            float4 vA = ((const float4*)(wv + (size_t)sA * DIM))[sub];
            float4 vB = ((const float4*)(wv + (size_t)sB * DIM))[sub];
            ax += vA.x * cA; ay += vA.y * cA; az += vA.z * cA; aw += vA.w * cA;
            ax += vB.x * cB; ay += vB.y * cB; az += vB.z * cB; aw += vB.w * cB;
        }
        if (j < rounds) {
            int l0 = 4 * j + g;
            int   sA = __shfl(s0, l0, 64);
            float cA = __shfl(cf0, l0, 64);
            float4 vA = ((const float4*)(wv + (size_t)sA * DIM))[sub];
            ax += vA.x * cA; ay += vA.y * cA; az += vA.z * cA; aw += vA.w * cA;
        }
        ax += __shfl_xor(ax, 16, 64); ay += __shfl_xor(ay, 16, 64);
        az += __shfl_xor(az, 16, 64); aw += __shfl_xor(aw, 16, 64);
        ax += __shfl_xor(ax, 32, 64); ay += __shfl_xor(ay, 32, 64);
        az += __shfl_xor(az, 32, 64); aw += __shfl_xor(aw, 32, 64);
        if (g == 0) {
            float4 o; o.x = ax; o.y = ay; o.z = az; o.w = aw;
            ((float4*)(out + (size_t)node * DIM))[sub] = o;
        }
    } else {
        double denom = 0.0;
        for (int base = 0; base < deg; base += 64) {
            int m = deg - base; if (m > 64) m = 64;
            double c = 0.0;
            if (lane < m) {
                int s = csr_src[start + base + lane];
                c = h_src[s] + hd;
            }
            #pragma unroll
            for (int off = 32; off > 0; off >>= 1) c += __shfl_xor(c, off, 64);
            denom += c;
        }
        double inv = 1.0 / denom;
        float acc = 0.f;
        for (int base = 0; base < deg; base += 64) {
            int m = deg - base; if (m > 64) m = 64;
            int s1 = 0; float cf1 = 0.f;
            if (lane < m) {
                s1 = csr_src[start + base + lane];
                cf1 = (float)((h_src[s1] + hd) * inv);
            }
            for (int j = 0; j < m; ++j) {
                int s = lane_bci(s1, j);
                float cf = lane_bcf(cf1, j);
                acc += wv[(size_t)s * DIM + lane] * cf;
            }
        }
        out[(size_t)node * DIM + lane] = acc;
    }
}

// ---------------------------------------------------------------------------
// Launch
// ---------------------------------------------------------------------------
extern "C" void kernel_launch(void* const* d_in, const int* in_sizes, int n_in,
                              void* d_out, int out_size, void* d_ws, size_t ws_size,
                              hipStream_t stream) {
    const float* d_u = (const float*)d_in[0];
    const float* p_u = (const float*)d_in[1];
    const float* w_q = (const float*)d_in[2];
    const float* w_k = (const float*)d_in[3];
    const float* w_v = (const float*)d_in[4];
    const float* e1  = (const float*)d_in[5];
    const float* e2  = (const float*)d_in[6];
    const int*   src = (const int*)d_in[7];
    const int*   dst = (const int*)d_in[8];
    float* out = (float*)d_out;

    // Workspace: doubles first (8B aligned), then floats, then ints.
    double* a      = (double*)d_ws;
    double* b      = a + DIM;
    double* h_src  = b + DIM;
    double* h_dst  = h_src + N_NODES;
    float*  wv     = (float*)(h_dst + N_NODES);       // N_NODES*DIM floats
    int*    cnt    = (int*)(wv + (size_t)N_NODES * DIM);
    int*    row    = cnt + N_NODES;
    int*    bsum   = row + N_NODES;                   // 128 ints
    int*    cnt8   = bsum + 128;                      // NCOPY*N_NODES ints
    int*    rank   = cnt8 + (size_t)NCOPY * N_NODES;  // N_EDGES ints
    int*    csr_src= rank + N_EDGES;                  // N_EDGES ints

    vec_precompute<<<1, 128, 0, stream>>>(w_q, w_k, e1, e2, a, b);

    hipMemsetAsync(cnt8, 0, sizeof(int) * (size_t)NCOPY * N_NODES, stream);

    hist_kernel<<<HIST_BLKS, 256, 0, stream>>>(dst, cnt8, rank);

    node_wave<<<1024, 256, 0, stream>>>(
        d_u, p_u, w_v, a, b, h_src, h_dst, wv);

    scan1_kernel<<<N_SCAN_BLKS, SCAN_BLK, 0, stream>>>(cnt8, cnt, row, bsum);
    scan23_kernel<<<(N_NODES + 255) / 256, 256, 0, stream>>>(row, bsum);

    build_kernel<<<(N_EDGES + 255) / 256, 256, 0, stream>>>(
        src, dst, row, cnt8, rank, csr_src);

    node_gather<<<(N_NODES * 64 + 255) / 256, 256, 0, stream>>>(
        row, cnt, csr_src, h_src, h_dst, wv, out);
}